// Round 10
// baseline (212.684 us; speedup 1.0000x reference)
//
#include <hip/hip_runtime.h>
#include <hip/hip_bf16.h>
#include <math.h>

// Problem constants
#define SEQ   2048
#define HID   1024
#define NH    16
#define NKV   4
#define DH    64
#define GQ    (NH / NKV)
#define NQKV  1536          // fused QKV output width
#define LQKV  1536          // row stride of fused QKV output
#define KT    32            // attention key-tile (register-direct, no barriers)
#define CH    512           // split-K chunk of keys (4 chunks)
#define NCH   (SEQ / CH)    // 4
#define PPS   40            // Pst row stride (u16)

typedef __attribute__((ext_vector_type(8))) short bf16x8;
typedef __attribute__((ext_vector_type(4))) float f32x4;
typedef unsigned short u16;
typedef unsigned int u32;

__device__ __forceinline__ u16 f2bf(float f) {
    union { float f; unsigned u; } x; x.f = f;
    unsigned r = x.u + 0x7fffu + ((x.u >> 16) & 1u);   // RNE
    return (u16)(r >> 16);
}
__device__ __forceinline__ u32 pk2bf(float lo, float hi) {
    return (u32)f2bf(lo) | ((u32)f2bf(hi) << 16);
}
// async global->LDS, 16B per lane; LDS dest = wave-uniform base + lane*16
__device__ __forceinline__ void load_lds16(const u16* g, u16* l) {
    __builtin_amdgcn_global_load_lds(
        (const __attribute__((address_space(1))) unsigned int*)g,
        (__attribute__((address_space(3))) unsigned int*)l, 16, 0, 0);
}

// ---------------------------------------------------------------------------
// Setup: weight transposes (z=0..3) + X fp32->bf16 convert (z=4), one launch.
// Grid (64, 32, 5), block 256.
// ---------------------------------------------------------------------------
__global__ __launch_bounds__(256) void setup(const float* __restrict__ X,
                                             const float* __restrict__ Wq,
                                             const float* __restrict__ Wk,
                                             const float* __restrict__ Wv,
                                             const float* __restrict__ Wo,
                                             u16* __restrict__ Xb,
                                             u16* __restrict__ Wt,
                                             u16* __restrict__ WoT) {
    const int z = blockIdx.z;
    if (z == 4) {
        const int idx = ((int)blockIdx.y * 64 + (int)blockIdx.x) * 256 + threadIdx.x;
        const float4 v = ((const float4*)X)[idx];
        ushort4 o;
        o.x = f2bf(v.x); o.y = f2bf(v.y); o.z = f2bf(v.z); o.w = f2bf(v.w);
        ((ushort4*)Xb)[idx] = o;
        return;
    }
    const float* in; u16* out; int N;
    if (z == 0)      { in = Wq; out = Wt;                             N = HID; }
    else if (z == 1) { in = Wk; out = Wt + (size_t)HID * HID;         N = 256; }
    else if (z == 2) { in = Wv; out = Wt + (size_t)(HID + 256) * HID; N = 256; }
    else             { in = Wo; out = WoT;                            N = HID; }

    const int n0 = blockIdx.x * 32;
    if (n0 >= N) return;
    const int k0 = blockIdx.y * 32;

    __shared__ float t[32][33];
    const int tx = threadIdx.x & 31;
    const int ty = threadIdx.x >> 5;
    #pragma unroll
    for (int i = 0; i < 4; ++i)
        t[ty + i * 8][tx] = in[(size_t)(k0 + ty + i * 8) * N + n0 + tx];
    __syncthreads();
    #pragma unroll
    for (int i = 0; i < 4; ++i)
        out[(size_t)(n0 + ty + i * 8) * HID + k0 + tx] = f2bf(t[tx][ty + i * 8]);
}

// ---------------------------------------------------------------------------
// bf16 MFMA GEMM v2 (unchanged from round 9): single-barrier, B double-
// buffered via async global->LDS, A-fragments direct from global.
// BM=128, BN=64, BK=32. Grid: (N/64, M/128).
// ---------------------------------------------------------------------------
__global__ __launch_bounds__(256) void gemm_v2(const u16* __restrict__ A,
                                               const u16* __restrict__ Bt,
                                               float* __restrict__ C,
                                               int K, int ldc) {
    __shared__ u16 Bs[2][64 * 32];

    const int tid  = threadIdx.x;
    const int lane = tid & 63;
    const int w    = tid >> 6;
    const int c    = lane & 15;
    const int quad = lane >> 4;
    const int m0   = blockIdx.y * 128;
    const int n0   = blockIdx.x * 64;

    const u16* gB  = Bt + (size_t)(n0 + w * 16 + (lane >> 2)) * K + (lane & 3) * 8;
    u16* const bdst = (u16*)&Bs[0][0] + (w * 16) * 32;

    const u16* gA0 = A + (size_t)(m0 + w * 32 + c) * K + quad * 8;
    const u16* gA1 = gA0 + (size_t)16 * K;

    const int T = K / 32;

    f32x4 acc[2][4];
    #pragma unroll
    for (int mt = 0; mt < 2; ++mt)
        #pragma unroll
        for (int nt = 0; nt < 4; ++nt)
            acc[mt][nt] = (f32x4){0.f, 0.f, 0.f, 0.f};

    bf16x8 afc[2], afn[2];
    afc[0] = *(const bf16x8*)gA0;
    afc[1] = *(const bf16x8*)gA1;
    load_lds16(gB, bdst);

    for (int t = 0; t < T; ++t) {
        __syncthreads();
        if (t + 1 < T) {
            load_lds16(gB + (t + 1) * 32, bdst + ((t + 1) & 1) * (64 * 32));
            afn[0] = *(const bf16x8*)(gA0 + (t + 1) * 32);
            afn[1] = *(const bf16x8*)(gA1 + (t + 1) * 32);
        }
        bf16x8 bfr[4];
        #pragma unroll
        for (int nt = 0; nt < 4; ++nt)
            bfr[nt] = *(const bf16x8*)&Bs[t & 1][(nt * 16 + c) * 32 + quad * 8];
        #pragma unroll
        for (int mt = 0; mt < 2; ++mt)
            #pragma unroll
            for (int nt = 0; nt < 4; ++nt)
                acc[mt][nt] = __builtin_amdgcn_mfma_f32_16x16x32_bf16(afc[mt], bfr[nt], acc[mt][nt], 0, 0, 0);
        afc[0] = afn[0];
        afc[1] = afn[1];
    }

    #pragma unroll
    for (int mt = 0; mt < 2; ++mt)
        #pragma unroll
        for (int nt = 0; nt < 4; ++nt)
            #pragma unroll
            for (int rg = 0; rg < 4; ++rg)
                C[(size_t)(m0 + w * 32 + mt * 16 + quad * 4 + rg) * ldc + n0 + nt * 16 + c] = acc[mt][nt][rg];
}

// ---------------------------------------------------------------------------
// Post-QKV processing: RoPE on Q and K, emit bf16 buffers:
//   Qb [s][h*64+d] (pre-scaled by 1/8), Kb [kh][s][d], VTg [kh][d][s].
// ---------------------------------------------------------------------------
__global__ __launch_bounds__(256) void postprocess(const float* __restrict__ QKV,
                                                   u16* __restrict__ Qb,
                                                   u16* __restrict__ Kb,
                                                   u16* __restrict__ VTg) {
    const int s   = blockIdx.x;
    const int tid = threadIdx.x;
    const float* row = QKV + (size_t)s * LQKV;
    const float ln_scale = 9.210340371976184f / 32.0f;   // ln(10000)/32

    #pragma unroll
    for (int it = 0; it < 2; ++it) {
        const int p = tid + it * 256;
        const int j = p & 31;
        const float inv_freq = __expf(-(float)((2 * j) & 31) * ln_scale);
        float sn, cs;
        __sincosf((float)s * inv_freq, &sn, &cs);
        const float xe = row[2 * p], xo = row[2 * p + 1];
        Qb[(size_t)s * HID + 2 * p]     = f2bf((xe * cs - xo * sn) * 0.125f);
        Qb[(size_t)s * HID + 2 * p + 1] = f2bf((xe * sn + xo * cs) * 0.125f);
    }
    if (tid < 128) {
        const int p  = tid;
        const int j  = p & 31;
        const int kh = p >> 5;
        const int d  = (2 * p) & 63;
        const float inv_freq = __expf(-(float)((2 * j) & 31) * ln_scale);
        float sn, cs;
        __sincosf((float)s * inv_freq, &sn, &cs);
        const float xe = row[1024 + 2 * p], xo = row[1024 + 2 * p + 1];
        u16* kr = Kb + ((size_t)kh * SEQ + s) * DH;
        kr[d]     = f2bf(xe * cs - xo * sn);
        kr[d + 1] = f2bf(xe * sn + xo * cs);
    }
    {
        const int c = tid;
        const int kh = c >> 6, d = c & 63;
        VTg[((size_t)kh * DH + d) * SEQ + s] = f2bf(row[1280 + c]);
    }
}

// ---------------------------------------------------------------------------
// MFMA flash attention v5: BARRIER-FREE, register-direct K/V.
//   S^T = K·Q^T ; O^T = V^T·P^T  (no-max exp; split-K partials sum linearly)
// All MFMA operand fragments load 16B/lane DIRECTLY from global (K/V are
// L2-resident, 256 KB/head); only P^T round-trips per-wave LDS. Zero
// __syncthreads. Block = 4 waves = 4 q-heads of one kv-head (same K/V
// addresses -> L1 reuse); wave = 16 queries x one CH chunk.
// Grid (SEQ/16=128 reversed, NKV, NCH). K-frags of tile t+1 prefetched
// during tile t; V-frags issued before the exp block.
// ---------------------------------------------------------------------------
__global__ __launch_bounds__(256) void attn_kernel(const u16* __restrict__ Qb,
                                                   const u16* __restrict__ Kb,
                                                   const u16* __restrict__ VTg,
                                                   float* __restrict__ Opart,
                                                   float* __restrict__ lpart) {
    __shared__ u16 Pst[4][16 * PPS];   // per-wave [q][key]

    const int tid  = threadIdx.x;
    const int lane = tid & 63;
    const int w    = tid >> 6;
    const int c    = lane & 15;
    const int quad = lane >> 4;
    const int kh   = blockIdx.y;
    const int z    = blockIdx.z;
    const int qt   = (SEQ / 16 - 1) - (int)blockIdx.x;   // heavy first
    const int q0   = qt * 16;
    const int h    = kh * GQ + w;

    const int kstart = z * CH;
    const int klim   = q0 + 16;
    if (kstart >= klim) return;                 // empty chunk
    const int kend   = (klim < kstart + CH) ? klim : (kstart + CH);
    const int ntiles = (kend - kstart + KT - 1) / KT;

    // Q B-fragments (loop-invariant): B[k=d=ks*32+quad*8+j][n=q=c]
    bf16x8 qf[2];
    #pragma unroll
    for (int ks = 0; ks < 2; ++ks)
        qf[ks] = *(const bf16x8*)&Qb[(size_t)(q0 + c) * HID + h * DH + ks * 32 + quad * 8];

    // per-lane fragment base pointers
    const u16* Kfrag = Kb  + ((size_t)kh * SEQ + kstart + c) * DH + quad * 8;  // + key*DH + ks*32
    const u16* Vfrag = VTg + ((size_t)kh * DH + c) * SEQ + kstart + quad * 8;  // + d16*16*SEQ + kt

    f32x4 accO[4];
    #pragma unroll
    for (int nt = 0; nt < 4; ++nt) accO[nt] = (f32x4){0.f, 0.f, 0.f, 0.f};
    float l = 0.f;

    // prologue: K A-frags for tile 0.  kf[nS][ks]: A[m=key=nS*16+c][k=ks*32+quad*8+j]
    bf16x8 kf[2][2], kn[2][2];
    #pragma unroll
    for (int nS = 0; nS < 2; ++nS)
        #pragma unroll
        for (int ks = 0; ks < 2; ++ks)
            kf[nS][ks] = *(const bf16x8*)(Kfrag + (size_t)(nS * 16) * DH + ks * 32);

    for (int t = 0; t < ntiles; ++t) {
        const int kt0 = t * KT;   // relative to kstart

        // ---- V^T A-frags for this tile (issued early; consumed at PV)
        bf16x8 vf[4];
        #pragma unroll
        for (int nt = 0; nt < 4; ++nt)
            vf[nt] = *(const bf16x8*)(Vfrag + (size_t)(nt * 16) * SEQ + kt0);

        // ---- S^T = K·Q^T (kf already resident)
        f32x4 accS[2];
        #pragma unroll
        for (int nS = 0; nS < 2; ++nS) accS[nS] = (f32x4){0.f, 0.f, 0.f, 0.f};
        #pragma unroll
        for (int nS = 0; nS < 2; ++nS)
            #pragma unroll
            for (int ks = 0; ks < 2; ++ks)
                accS[nS] = __builtin_amdgcn_mfma_f32_16x16x32_bf16(kf[nS][ks], qf[ks], accS[nS], 0, 0, 0);

        // ---- prefetch next tile's K A-frags
        if (t + 1 < ntiles) {
            #pragma unroll
            for (int nS = 0; nS < 2; ++nS)
                #pragma unroll
                for (int ks = 0; ks < 2; ++ks)
                    kn[nS][ks] = *(const bf16x8*)(Kfrag + (size_t)(kt0 + KT + nS * 16) * DH + ks * 32);
        }

        // ---- mask + exp (row=key, col=q=q0+c); packed P^T to per-wave LDS
        const int q = q0 + c;
        #pragma unroll
        for (int nS = 0; nS < 2; ++nS) {
            const int key = kstart + kt0 + nS * 16 + quad * 4;
            const float p0 = (key + 0 <= q) ? __expf(accS[nS][0]) : 0.f;
            const float p1 = (key + 1 <= q) ? __expf(accS[nS][1]) : 0.f;
            const float p2 = (key + 2 <= q) ? __expf(accS[nS][2]) : 0.f;
            const float p3 = (key + 3 <= q) ? __expf(accS[nS][3]) : 0.f;
            l += (p0 + p1) + (p2 + p3);
            u32* dst = (u32*)&Pst[w][c * PPS + nS * 16 + quad * 4];
            dst[0] = pk2bf(p0, p1);
            dst[1] = pk2bf(p2, p3);
        }
        __threadfence_block();   // same-wave LDS write->read ordering

        // ---- O^T += V^T·P^T
        const bf16x8 pf = *(const bf16x8*)&Pst[w][c * PPS + quad * 8];
        #pragma unroll
        for (int nt = 0; nt < 4; ++nt)
            accO[nt] = __builtin_amdgcn_mfma_f32_16x16x32_bf16(vf[nt], pf, accO[nt], 0, 0, 0);

        #pragma unroll
        for (int nS = 0; nS < 2; ++nS)
            #pragma unroll
            for (int ks = 0; ks < 2; ++ks)
                kf[nS][ks] = kn[nS][ks];
    }

    // ---- per-column l: reduce across quads; store partials (unnormalized)
    l += __shfl_xor(l, 16);
    l += __shfl_xor(l, 32);
    if (quad == 0)
        lpart[((size_t)z * SEQ + q0 + c) * NH + h] = l;

    float* Op = Opart + ((size_t)z * SEQ + q0 + c) * HID + h * DH;
    #pragma unroll
    for (int nt = 0; nt < 4; ++nt)
        *(f32x4*)&Op[nt * 16 + quad * 4] = accO[nt];
}

// ---------------------------------------------------------------------------
// Merge split-K partials: At[q] = sum_z O_z[q] / sum_z l_z[q], bf16.
// Chunk z contributes iff z*CH < (q & ~15) + 16.
// ---------------------------------------------------------------------------
__global__ __launch_bounds__(256) void attn_reduce(const float* __restrict__ Opart,
                                                   const float* __restrict__ lpart,
                                                   u16* __restrict__ At) {
    const int idx = blockIdx.x * 256 + threadIdx.x;   // float4 index
    const int q  = idx >> 8;
    const int h  = (idx & 255) >> 4;
    const int klim = (q & ~15) + 16;
    float4 o = ((const float4*)Opart)[idx];
    float  l = lpart[q * NH + h];
    #pragma unroll
    for (int z = 1; z < NCH; ++z) {
        if (z * CH < klim) {
            const float4 o1 = ((const float4*)Opart)[idx + z * (SEQ * HID / 4)];
            o.x += o1.x; o.y += o1.y; o.z += o1.z; o.w += o1.w;
            l += lpart[(z * SEQ + q) * NH + h];
        }
    }
    const float inv = 1.0f / l;
    ushort4 r;
    r.x = f2bf(o.x * inv); r.y = f2bf(o.y * inv);
    r.z = f2bf(o.z * inv); r.w = f2bf(o.w * inv);
    ((ushort4*)At)[idx] = r;
}

// ---------------------------------------------------------------------------
extern "C" void kernel_launch(void* const* d_in, const int* in_sizes, int n_in,
                              void* d_out, int out_size, void* d_ws, size_t ws_size,
                              hipStream_t stream) {
    const float* X  = (const float*)d_in[0];
    const float* Wq = (const float*)d_in[1];
    const float* Wk = (const float*)d_in[2];
    const float* Wv = (const float*)d_in[3];
    const float* Wo = (const float*)d_in[4];
    float* out = (float*)d_out;

    // workspace layout (Opart overlaps dead QKVc to bound footprint)
    u16* Wt     = (u16*)d_ws;                        // 1536 x 1024 bf16
    u16* WoT    = Wt + (size_t)NQKV * HID;           // 1024 x 1024
    u16* Xb     = WoT + (size_t)HID * HID;           // 2048 x 1024
    u16* At     = Xb + (size_t)SEQ * HID;            // 2048 x 1024
    u16* Qb     = At + (size_t)SEQ * HID;            // 2048 x 1024
    u16* Kb     = Qb + (size_t)SEQ * HID;            // 4 x 2048 x 64
    u16* VTg    = Kb + (size_t)NKV * SEQ * DH;       // 4 x 64 x 2048
    float* QKVc = (float*)(VTg + (size_t)NKV * DH * SEQ);   // 2048 x 1536 fp32
    float* Opart = QKVc;                             // reuse: NCH x 2048 x 1024 fp32
    float* lpart = Opart + (size_t)NCH * SEQ * HID;  // NCH x 2048 x 16 fp32

    dim3 blk(256);

    setup<<<dim3(64, 32, 5), blk, 0, stream>>>(X, Wq, Wk, Wv, Wo, Xb, Wt, WoT);

    gemm_v2<<<dim3(NQKV / 64, SEQ / 128), blk, 0, stream>>>(Xb, Wt, QKVc, HID, LQKV);

    postprocess<<<SEQ, blk, 0, stream>>>(QKVc, Qb, Kb, VTg);

    attn_kernel<<<dim3(SEQ / 16, NKV, NCH), blk, 0, stream>>>(Qb, Kb, VTg, Opart, lpart);

    attn_reduce<<<(SEQ * HID / 4) / 256, blk, 0, stream>>>(Opart, lpart, At);

    gemm_v2<<<dim3(HID / 64, SEQ / 128), blk, 0, stream>>>(At, WoT, out, HID, HID);
}

// Round 11
// 154.124 us; speedup vs baseline: 1.3800x; 1.3800x over previous
//
#include <hip/hip_runtime.h>
#include <hip/hip_bf16.h>
#include <math.h>

// Problem constants
#define SEQ   2048
#define HID   1024
#define NH    16
#define NKV   4
#define DH    64
#define GQ    (NH / NKV)
#define NQKV  1536          // fused QKV output width
#define LQKV  1536          // row stride of fused QKV output
#define KT    64            // attention key-tile
#define QB    32            // queries per block (2 q-frags per wave)
#define CH    512           // split-K chunk of keys (4 chunks)
#define NCH   (SEQ / CH)    // 4
#define PSTR  72            // LDS row stride (u16)

typedef __attribute__((ext_vector_type(8))) short bf16x8;
typedef __attribute__((ext_vector_type(4))) float f32x4;
typedef unsigned short u16;
typedef unsigned int u32;

__device__ __forceinline__ u16 f2bf(float f) {
    union { float f; unsigned u; } x; x.f = f;
    unsigned r = x.u + 0x7fffu + ((x.u >> 16) & 1u);   // RNE
    return (u16)(r >> 16);
}
__device__ __forceinline__ u32 pk2bf(float lo, float hi) {
    return (u32)f2bf(lo) | ((u32)f2bf(hi) << 16);
}
// async global->LDS, 16B per lane; LDS dest = wave-uniform base + lane*16
__device__ __forceinline__ void load_lds16(const u16* g, u16* l) {
    __builtin_amdgcn_global_load_lds(
        (const __attribute__((address_space(1))) unsigned int*)g,
        (__attribute__((address_space(3))) unsigned int*)l, 16, 0, 0);
}

// ---------------------------------------------------------------------------
// Setup: weight transposes (z=0..3) + X fp32->bf16 convert (z=4), one launch.
// ---------------------------------------------------------------------------
__global__ __launch_bounds__(256) void setup(const float* __restrict__ X,
                                             const float* __restrict__ Wq,
                                             const float* __restrict__ Wk,
                                             const float* __restrict__ Wv,
                                             const float* __restrict__ Wo,
                                             u16* __restrict__ Xb,
                                             u16* __restrict__ Wt,
                                             u16* __restrict__ WoT) {
    const int z = blockIdx.z;
    if (z == 4) {
        const int idx = ((int)blockIdx.y * 64 + (int)blockIdx.x) * 256 + threadIdx.x;
        const float4 v = ((const float4*)X)[idx];
        ushort4 o;
        o.x = f2bf(v.x); o.y = f2bf(v.y); o.z = f2bf(v.z); o.w = f2bf(v.w);
        ((ushort4*)Xb)[idx] = o;
        return;
    }
    const float* in; u16* out; int N;
    if (z == 0)      { in = Wq; out = Wt;                             N = HID; }
    else if (z == 1) { in = Wk; out = Wt + (size_t)HID * HID;         N = 256; }
    else if (z == 2) { in = Wv; out = Wt + (size_t)(HID + 256) * HID; N = 256; }
    else             { in = Wo; out = WoT;                            N = HID; }

    const int n0 = blockIdx.x * 32;
    if (n0 >= N) return;
    const int k0 = blockIdx.y * 32;

    __shared__ float t[32][33];
    const int tx = threadIdx.x & 31;
    const int ty = threadIdx.x >> 5;
    #pragma unroll
    for (int i = 0; i < 4; ++i)
        t[ty + i * 8][tx] = in[(size_t)(k0 + ty + i * 8) * N + n0 + tx];
    __syncthreads();
    #pragma unroll
    for (int i = 0; i < 4; ++i)
        out[(size_t)(n0 + ty + i * 8) * HID + k0 + tx] = f2bf(t[tx][ty + i * 8]);
}

// ---------------------------------------------------------------------------
// bf16 MFMA GEMM v3: BM=64, BN=64, BK=32 — small tile for occupancy.
// 256 thr = 4 waves; wave w: rows m0+w*16..+15, all 64 n-cols (4 n-frags,
// 4 MFMA per K-tile). A-fragments direct from global (16B/lane); B async-
// staged to LDS, double-buffered, single barrier per iter.
// Grid: (N/64, M/64) -> QKV 24x32=768 blocks, Wo 16x32=512 blocks.
// ---------------------------------------------------------------------------
__global__ __launch_bounds__(256) void gemm64(const u16* __restrict__ A,
                                              const u16* __restrict__ Bt,
                                              float* __restrict__ C,
                                              int K, int ldc) {
    __shared__ u16 Bs[2][64 * 32];

    const int tid  = threadIdx.x;
    const int lane = tid & 63;
    const int w    = tid >> 6;
    const int c    = lane & 15;
    const int quad = lane >> 4;
    const int m0   = blockIdx.y * 64;
    const int n0   = blockIdx.x * 64;

    // B staging: wave w stages rows n0+w*16..+15 of the BK slice
    const u16* gB  = Bt + (size_t)(n0 + w * 16 + (lane >> 2)) * K + (lane & 3) * 8;
    u16* const bdst = (u16*)&Bs[0][0] + (w * 16) * 32;

    // A direct fragment: lane (c,quad) -> row m0+w*16+c, k-chunk quad*8
    const u16* gA = A + (size_t)(m0 + w * 16 + c) * K + quad * 8;

    const int T = K / 32;

    f32x4 acc[4];
    #pragma unroll
    for (int nt = 0; nt < 4; ++nt) acc[nt] = (f32x4){0.f, 0.f, 0.f, 0.f};

    bf16x8 afc, afn;
    afc = *(const bf16x8*)gA;
    load_lds16(gB, bdst);

    for (int t = 0; t < T; ++t) {
        __syncthreads();   // tile t staged; buf[(t+1)&1] free
        if (t + 1 < T) {
            load_lds16(gB + (t + 1) * 32, bdst + ((t + 1) & 1) * (64 * 32));
            afn = *(const bf16x8*)(gA + (t + 1) * 32);
        }
        bf16x8 bfr[4];
        #pragma unroll
        for (int nt = 0; nt < 4; ++nt)
            bfr[nt] = *(const bf16x8*)&Bs[t & 1][(nt * 16 + c) * 32 + quad * 8];
        #pragma unroll
        for (int nt = 0; nt < 4; ++nt)
            acc[nt] = __builtin_amdgcn_mfma_f32_16x16x32_bf16(afc, bfr[nt], acc[nt], 0, 0, 0);
        afc = afn;
    }

    // C/D layout: col = lane&15, row = quad*4 + reg
    #pragma unroll
    for (int nt = 0; nt < 4; ++nt)
        #pragma unroll
        for (int rg = 0; rg < 4; ++rg)
            C[(size_t)(m0 + w * 16 + quad * 4 + rg) * ldc + n0 + nt * 16 + c] = acc[nt][rg];
}

// ---------------------------------------------------------------------------
// Post-QKV processing: RoPE on Q and K, emit bf16 buffers:
//   Qb [s][h*64+d] (pre-scaled by 1/8), Kb [kh][s][d], VTg [kh][d][s].
// ---------------------------------------------------------------------------
__global__ __launch_bounds__(256) void postprocess(const float* __restrict__ QKV,
                                                   u16* __restrict__ Qb,
                                                   u16* __restrict__ Kb,
                                                   u16* __restrict__ VTg) {
    const int s   = blockIdx.x;
    const int tid = threadIdx.x;
    const float* row = QKV + (size_t)s * LQKV;
    const float ln_scale = 9.210340371976184f / 32.0f;   // ln(10000)/32

    #pragma unroll
    for (int it = 0; it < 2; ++it) {
        const int p = tid + it * 256;
        const int j = p & 31;
        const float inv_freq = __expf(-(float)((2 * j) & 31) * ln_scale);
        float sn, cs;
        __sincosf((float)s * inv_freq, &sn, &cs);
        const float xe = row[2 * p], xo = row[2 * p + 1];
        Qb[(size_t)s * HID + 2 * p]     = f2bf((xe * cs - xo * sn) * 0.125f);
        Qb[(size_t)s * HID + 2 * p + 1] = f2bf((xe * sn + xo * cs) * 0.125f);
    }
    if (tid < 128) {
        const int p  = tid;
        const int j  = p & 31;
        const int kh = p >> 5;
        const int d  = (2 * p) & 63;
        const float inv_freq = __expf(-(float)((2 * j) & 31) * ln_scale);
        float sn, cs;
        __sincosf((float)s * inv_freq, &sn, &cs);
        const float xe = row[1024 + 2 * p], xo = row[1024 + 2 * p + 1];
        u16* kr = Kb + ((size_t)kh * SEQ + s) * DH;
        kr[d]     = f2bf(xe * cs - xo * sn);
        kr[d + 1] = f2bf(xe * sn + xo * cs);
    }
    {
        const int c = tid;
        const int kh = c >> 6, d = c & 63;
        VTg[((size_t)kh * DH + d) * SEQ + s] = f2bf(row[1280 + c]);
    }
}

// ---------------------------------------------------------------------------
// MFMA flash attention (exact round-8 version): QB=32 + split-K CH=512.
//   S^T = K·Q^T ; O^T = V^T·P^T  (no-max exp -> chunk partials sum linearly)
// Block = 4 waves = 4 q-heads of kv-head kh; LDS-staged K/V, 2 barriers.
// Grid (SEQ/QB=64 reversed, NKV, NCH=4).
// ---------------------------------------------------------------------------
__global__ __launch_bounds__(256) void attn_kernel(const u16* __restrict__ Qb,
                                                   const u16* __restrict__ Kb,
                                                   const u16* __restrict__ VTg,
                                                   float* __restrict__ Opart,
                                                   float* __restrict__ lpart) {
    __shared__ u16 Kst[64 * PSTR];      // [key][d]
    __shared__ u16 VTst[64 * PSTR];     // [d][key]
    __shared__ u16 Pst[4][QB * PSTR];   // per-wave [q][key]

    const int tid  = threadIdx.x;
    const int lane = tid & 63;
    const int w    = tid >> 6;
    const int c    = lane & 15;
    const int quad = lane >> 4;
    const int kh   = blockIdx.y;
    const int z    = blockIdx.z;
    const int qt   = (SEQ / QB - 1) - (int)blockIdx.x;   // heavy first
    const int q0   = qt * QB;
    const int h    = kh * GQ + w;

    const int kstart = z * CH;
    const int klim   = q0 + QB;
    if (kstart >= klim) return;                 // empty chunk
    const int kend   = (klim < kstart + CH) ? klim : (kstart + CH);
    const int ntiles = (kend - kstart + KT - 1) / KT;

    bf16x8 qf[2][2];
    #pragma unroll
    for (int g = 0; g < 2; ++g)
        #pragma unroll
        for (int ks = 0; ks < 2; ++ks)
            qf[g][ks] = *(const bf16x8*)&Qb[(size_t)(q0 + g * 16 + c) * HID + h * DH + ks * 32 + quad * 8];

    f32x4 accO[4][2];
    #pragma unroll
    for (int nt = 0; nt < 4; ++nt)
        #pragma unroll
        for (int g = 0; g < 2; ++g)
            accO[nt][g] = (f32x4){0.f, 0.f, 0.f, 0.f};
    float l[2] = {0.f, 0.f};

    for (int t = 0; t < ntiles; ++t) {
        const int kt0 = kstart + t * KT;
        __syncthreads();
        {
            const int r = tid >> 3, off = (tid & 7) * 8;
            const u16* kg = &Kb[((size_t)kh * SEQ + kt0 + r) * DH + off];
            *(uint4*)&Kst[r * PSTR + off]        = *(const uint4*)kg;
            *(uint4*)&Kst[(r + 32) * PSTR + off] = *(const uint4*)(kg + 32 * DH);
            const u16* vg = &VTg[((size_t)kh * DH + r) * SEQ + kt0 + off];
            *(uint4*)&VTst[r * PSTR + off]        = *(const uint4*)vg;
            *(uint4*)&VTst[(r + 32) * PSTR + off] = *(const uint4*)(vg + 32 * SEQ);
        }
        __syncthreads();

        f32x4 accS[4][2];
        #pragma unroll
        for (int nS = 0; nS < 4; ++nS)
            #pragma unroll
            for (int g = 0; g < 2; ++g)
                accS[nS][g] = (f32x4){0.f, 0.f, 0.f, 0.f};
        #pragma unroll
        for (int nS = 0; nS < 4; ++nS)
            #pragma unroll
            for (int ks = 0; ks < 2; ++ks) {
                const bf16x8 kf = *(const bf16x8*)&Kst[(nS * 16 + c) * PSTR + ks * 32 + quad * 8];
                #pragma unroll
                for (int g = 0; g < 2; ++g)
                    accS[nS][g] = __builtin_amdgcn_mfma_f32_16x16x32_bf16(kf, qf[g][ks], accS[nS][g], 0, 0, 0);
            }

        #pragma unroll
        for (int g = 0; g < 2; ++g) {
            const int q = q0 + g * 16 + c;
            #pragma unroll
            for (int nS = 0; nS < 4; ++nS) {
                const int key = kt0 + nS * 16 + quad * 4;
                const float p0 = (key + 0 <= q) ? __expf(accS[nS][g][0]) : 0.f;
                const float p1 = (key + 1 <= q) ? __expf(accS[nS][g][1]) : 0.f;
                const float p2 = (key + 2 <= q) ? __expf(accS[nS][g][2]) : 0.f;
                const float p3 = (key + 3 <= q) ? __expf(accS[nS][g][3]) : 0.f;
                l[g] += (p0 + p1) + (p2 + p3);
                u32* dst = (u32*)&Pst[w][(g * 16 + c) * PSTR + nS * 16 + quad * 4];
                dst[0] = pk2bf(p0, p1);
                dst[1] = pk2bf(p2, p3);
            }
        }
        __threadfence_block();

        #pragma unroll
        for (int ks2 = 0; ks2 < 2; ++ks2) {
            bf16x8 pf[2];
            #pragma unroll
            for (int g = 0; g < 2; ++g)
                pf[g] = *(const bf16x8*)&Pst[w][(g * 16 + c) * PSTR + ks2 * 32 + quad * 8];
            #pragma unroll
            for (int nt = 0; nt < 4; ++nt) {
                const bf16x8 vf = *(const bf16x8*)&VTst[(nt * 16 + c) * PSTR + ks2 * 32 + quad * 8];
                #pragma unroll
                for (int g = 0; g < 2; ++g)
                    accO[nt][g] = __builtin_amdgcn_mfma_f32_16x16x32_bf16(vf, pf[g], accO[nt][g], 0, 0, 0);
            }
        }
    }

    #pragma unroll
    for (int g = 0; g < 2; ++g) {
        float lg = l[g];
        lg += __shfl_xor(lg, 16);
        lg += __shfl_xor(lg, 32);
        if (quad == 0)
            lpart[((size_t)z * SEQ + q0 + g * 16 + c) * NH + h] = lg;

        float* Op = Opart + ((size_t)z * SEQ + q0 + g * 16 + c) * HID + h * DH;
        #pragma unroll
        for (int nt = 0; nt < 4; ++nt)
            *(f32x4*)&Op[nt * 16 + quad * 4] = accO[nt][g];
    }
}

// ---------------------------------------------------------------------------
// Merge split-K partials: At[q] = sum_z O_z[q] / sum_z l_z[q], bf16.
// ---------------------------------------------------------------------------
__global__ __launch_bounds__(256) void attn_reduce(const float* __restrict__ Opart,
                                                   const float* __restrict__ lpart,
                                                   u16* __restrict__ At) {
    const int idx = blockIdx.x * 256 + threadIdx.x;   // float4 index
    const int q  = idx >> 8;
    const int h  = (idx & 255) >> 4;
    const int klim = (q & ~(QB - 1)) + QB;
    float4 o = ((const float4*)Opart)[idx];
    float  l = lpart[q * NH + h];
    #pragma unroll
    for (int z = 1; z < NCH; ++z) {
        if (z * CH < klim) {
            const float4 o1 = ((const float4*)Opart)[idx + z * (SEQ * HID / 4)];
            o.x += o1.x; o.y += o1.y; o.z += o1.z; o.w += o1.w;
            l += lpart[(z * SEQ + q) * NH + h];
        }
    }
    const float inv = 1.0f / l;
    ushort4 r;
    r.x = f2bf(o.x * inv); r.y = f2bf(o.y * inv);
    r.z = f2bf(o.z * inv); r.w = f2bf(o.w * inv);
    ((ushort4*)At)[idx] = r;
}

// ---------------------------------------------------------------------------
extern "C" void kernel_launch(void* const* d_in, const int* in_sizes, int n_in,
                              void* d_out, int out_size, void* d_ws, size_t ws_size,
                              hipStream_t stream) {
    const float* X  = (const float*)d_in[0];
    const float* Wq = (const float*)d_in[1];
    const float* Wk = (const float*)d_in[2];
    const float* Wv = (const float*)d_in[3];
    const float* Wo = (const float*)d_in[4];
    float* out = (float*)d_out;

    // workspace layout (Opart overlaps dead QKVc to bound footprint)
    u16* Wt     = (u16*)d_ws;                        // 1536 x 1024 bf16
    u16* WoT    = Wt + (size_t)NQKV * HID;           // 1024 x 1024
    u16* Xb     = WoT + (size_t)HID * HID;           // 2048 x 1024
    u16* At     = Xb + (size_t)SEQ * HID;            // 2048 x 1024
    u16* Qb     = At + (size_t)SEQ * HID;            // 2048 x 1024
    u16* Kb     = Qb + (size_t)SEQ * HID;            // 4 x 2048 x 64
    u16* VTg    = Kb + (size_t)NKV * SEQ * DH;       // 4 x 64 x 2048
    float* QKVc = (float*)(VTg + (size_t)NKV * DH * SEQ);   // 2048 x 1536 fp32
    float* Opart = QKVc;                             // reuse: NCH x 2048 x 1024 fp32
    float* lpart = Opart + (size_t)NCH * SEQ * HID;  // NCH x 2048 x 16 fp32

    dim3 blk(256);

    setup<<<dim3(64, 32, 5), blk, 0, stream>>>(X, Wq, Wk, Wv, Wo, Xb, Wt, WoT);

    gemm64<<<dim3(NQKV / 64, SEQ / 64), blk, 0, stream>>>(Xb, Wt, QKVc, HID, LQKV);

    postprocess<<<SEQ, blk, 0, stream>>>(QKVc, Qb, Kb, VTg);

    attn_kernel<<<dim3(SEQ / QB, NKV, NCH), blk, 0, stream>>>(Qb, Kb, VTg, Opart, lpart);

    attn_reduce<<<(SEQ * HID / 4) / 256, blk, 0, stream>>>(Opart, lpart, At);

    gemm64<<<dim3(HID / 64, SEQ / 64), blk, 0, stream>>>(At, WoT, out, HID, HID);
}

// Round 12
// 141.125 us; speedup vs baseline: 1.5071x; 1.0921x over previous
//
#include <hip/hip_runtime.h>
#include <hip/hip_bf16.h>
#include <math.h>

// Problem constants
#define SEQ   2048
#define HID   1024
#define NH    16
#define NKV   4
#define DH    64
#define GQ    (NH / NKV)
#define NQKV  1536          // fused QKV output width
#define KT    64            // attention key-tile
#define QB    32            // queries per block (2 q-frags per wave)
#define CH    512           // split-K chunk of keys (4 chunks)
#define NCH   (SEQ / CH)    // 4
#define PSTR  72            // Pst row stride (u16)
#define LNSC  0.2878231366f // ln(10000)/32

typedef __attribute__((ext_vector_type(8))) short bf16x8;
typedef __attribute__((ext_vector_type(4))) float f32x4;
typedef unsigned short u16;
typedef unsigned int u32;

__device__ __forceinline__ u16 f2bf(float f) {
    union { float f; unsigned u; } x; x.f = f;
    unsigned r = x.u + 0x7fffu + ((x.u >> 16) & 1u);   // RNE
    return (u16)(r >> 16);
}
__device__ __forceinline__ u32 pk2bf(float lo, float hi) {
    return (u32)f2bf(lo) | ((u32)f2bf(hi) << 16);
}
// async global->LDS: per-lane global gather, LDS dest = wave-uniform base
// + lane*16B [guide §5 caveat — verified pattern]
__device__ __forceinline__ void load_lds16(const u16* g, u16* l) {
    __builtin_amdgcn_global_load_lds(
        (const __attribute__((address_space(1))) unsigned int*)g,
        (__attribute__((address_space(3))) unsigned int*)l, 16, 0, 0);
}

// ---------------------------------------------------------------------------
// Setup: weight transposes (z=0..3) + X fp32->bf16 convert (z=4), one launch.
// ---------------------------------------------------------------------------
__global__ __launch_bounds__(256) void setup(const float* __restrict__ X,
                                             const float* __restrict__ Wq,
                                             const float* __restrict__ Wk,
                                             const float* __restrict__ Wv,
                                             const float* __restrict__ Wo,
                                             u16* __restrict__ Xb,
                                             u16* __restrict__ Wt,
                                             u16* __restrict__ WoT) {
    const int z = blockIdx.z;
    if (z == 4) {
        const int idx = ((int)blockIdx.y * 64 + (int)blockIdx.x) * 256 + threadIdx.x;
        const float4 v = ((const float4*)X)[idx];
        ushort4 o;
        o.x = f2bf(v.x); o.y = f2bf(v.y); o.z = f2bf(v.z); o.w = f2bf(v.w);
        ((ushort4*)Xb)[idx] = o;
        return;
    }
    const float* in; u16* out; int N;
    if (z == 0)      { in = Wq; out = Wt;                             N = HID; }
    else if (z == 1) { in = Wk; out = Wt + (size_t)HID * HID;         N = 256; }
    else if (z == 2) { in = Wv; out = Wt + (size_t)(HID + 256) * HID; N = 256; }
    else             { in = Wo; out = WoT;                            N = HID; }

    const int n0 = blockIdx.x * 32;
    if (n0 >= N) return;
    const int k0 = blockIdx.y * 32;

    __shared__ float t[32][33];
    const int tx = threadIdx.x & 31;
    const int ty = threadIdx.x >> 5;
    #pragma unroll
    for (int i = 0; i < 4; ++i)
        t[ty + i * 8][tx] = in[(size_t)(k0 + ty + i * 8) * N + n0 + tx];
    __syncthreads();
    #pragma unroll
    for (int i = 0; i < 4; ++i)
        out[(size_t)(n0 + ty + i * 8) * HID + k0 + tx] = f2bf(t[tx][ty + i * 8]);
}

// ---------------------------------------------------------------------------
// QKV GEMM with fused RoPE epilogue. BM=64,BN=64,BK=32; grid (24, 32).
// Main loop = gemm64 (R11-proven). Epilogue routes by n0:
//   n0<1024: Q head -> rope, *0.125, Qb[s][h*64+d] bf16
//   n0<1280: K head -> rope, Kb[kh][s][d] bf16
//   else   : V head -> VTg[kh][d][s] bf16 (transposed, ushort4-packed)
// Rope pair (d, d^1) lives in lanes (c, c^1): one shfl_xor exchange.
// ---------------------------------------------------------------------------
__global__ __launch_bounds__(256) void gemm_qkv(const u16* __restrict__ A,
                                                const u16* __restrict__ Bt,
                                                u16* __restrict__ Qb,
                                                u16* __restrict__ Kb,
                                                u16* __restrict__ VTg) {
    __shared__ u16 Bs[2][64 * 32];

    const int tid  = threadIdx.x;
    const int lane = tid & 63;
    const int w    = tid >> 6;
    const int c    = lane & 15;
    const int quad = lane >> 4;
    const int m0   = blockIdx.y * 64;
    const int n0   = blockIdx.x * 64;

    const u16* gB  = Bt + (size_t)(n0 + w * 16 + (lane >> 2)) * HID + (lane & 3) * 8;
    u16* const bdst = (u16*)&Bs[0][0] + (w * 16) * 32;
    const u16* gA = A + (size_t)(m0 + w * 16 + c) * HID + quad * 8;

    f32x4 acc[4];
    #pragma unroll
    for (int nt = 0; nt < 4; ++nt) acc[nt] = (f32x4){0.f, 0.f, 0.f, 0.f};

    bf16x8 afc, afn;
    afc = *(const bf16x8*)gA;
    load_lds16(gB, bdst);

    for (int t = 0; t < HID / 32; ++t) {
        __syncthreads();
        if (t + 1 < HID / 32) {
            load_lds16(gB + (t + 1) * 32, bdst + ((t + 1) & 1) * (64 * 32));
            afn = *(const bf16x8*)(gA + (t + 1) * 32);
        }
        bf16x8 bfr[4];
        #pragma unroll
        for (int nt = 0; nt < 4; ++nt)
            bfr[nt] = *(const bf16x8*)&Bs[t & 1][(nt * 16 + c) * 32 + quad * 8];
        #pragma unroll
        for (int nt = 0; nt < 4; ++nt)
            acc[nt] = __builtin_amdgcn_mfma_f32_16x16x32_bf16(afc, bfr[nt], acc[nt], 0, 0, 0);
        afc = afn;
    }

    const int s0 = m0 + w * 16 + quad * 4;
    if (n0 < 1280) {
        // rope regions (Q or K)
        const bool isQ = (n0 < 1024);
        #pragma unroll
        for (int nt = 0; nt < 4; ++nt) {
            const int d = nt * 16 + c;
            const float inv_freq = __expf(-(float)(d & 30) * LNSC);
            const float sgn = (d & 1) ? 1.f : -1.f;
            #pragma unroll
            for (int rg = 0; rg < 4; ++rg) {
                const float self = acc[nt][rg];
                const float partner = __shfl_xor(self, 1);
                float sn, cs;
                __sincosf((float)(s0 + rg) * inv_freq, &sn, &cs);
                float o = fmaf(partner, sgn * sn, self * cs);
                if (isQ) {
                    Qb[(size_t)(s0 + rg) * HID + n0 + d] = f2bf(o * 0.125f);
                } else {
                    const int kh = (n0 - 1024) >> 6;
                    Kb[((size_t)kh * SEQ + s0 + rg) * DH + d] = f2bf(o);
                }
            }
        }
    } else {
        const int kh = (n0 - 1280) >> 6;
        #pragma unroll
        for (int nt = 0; nt < 4; ++nt) {
            const int d = nt * 16 + c;
            ushort4 o;
            o.x = f2bf(acc[nt][0]); o.y = f2bf(acc[nt][1]);
            o.z = f2bf(acc[nt][2]); o.w = f2bf(acc[nt][3]);
            *(ushort4*)&VTg[((size_t)kh * DH + d) * SEQ + s0] = o;
        }
    }
}

// ---------------------------------------------------------------------------
// bf16 MFMA GEMM (R11 gemm64, unchanged): BM=64,BN=64,BK=32, A direct,
// B async double-buffered, single barrier. Used for the Wo projection.
// ---------------------------------------------------------------------------
__global__ __launch_bounds__(256) void gemm64(const u16* __restrict__ A,
                                              const u16* __restrict__ Bt,
                                              float* __restrict__ C,
                                              int K, int ldc) {
    __shared__ u16 Bs[2][64 * 32];

    const int tid  = threadIdx.x;
    const int lane = tid & 63;
    const int w    = tid >> 6;
    const int c    = lane & 15;
    const int quad = lane >> 4;
    const int m0   = blockIdx.y * 64;
    const int n0   = blockIdx.x * 64;

    const u16* gB  = Bt + (size_t)(n0 + w * 16 + (lane >> 2)) * K + (lane & 3) * 8;
    u16* const bdst = (u16*)&Bs[0][0] + (w * 16) * 32;
    const u16* gA = A + (size_t)(m0 + w * 16 + c) * K + quad * 8;

    const int T = K / 32;

    f32x4 acc[4];
    #pragma unroll
    for (int nt = 0; nt < 4; ++nt) acc[nt] = (f32x4){0.f, 0.f, 0.f, 0.f};

    bf16x8 afc, afn;
    afc = *(const bf16x8*)gA;
    load_lds16(gB, bdst);

    for (int t = 0; t < T; ++t) {
        __syncthreads();
        if (t + 1 < T) {
            load_lds16(gB + (t + 1) * 32, bdst + ((t + 1) & 1) * (64 * 32));
            afn = *(const bf16x8*)(gA + (t + 1) * 32);
        }
        bf16x8 bfr[4];
        #pragma unroll
        for (int nt = 0; nt < 4; ++nt)
            bfr[nt] = *(const bf16x8*)&Bs[t & 1][(nt * 16 + c) * 32 + quad * 8];
        #pragma unroll
        for (int nt = 0; nt < 4; ++nt)
            acc[nt] = __builtin_amdgcn_mfma_f32_16x16x32_bf16(afc, bfr[nt], acc[nt], 0, 0, 0);
        afc = afn;
    }

    #pragma unroll
    for (int nt = 0; nt < 4; ++nt)
        #pragma unroll
        for (int rg = 0; rg < 4; ++rg)
            C[(size_t)(m0 + w * 16 + quad * 4 + rg) * ldc + n0 + nt * 16 + c] = acc[nt][rg];
}

// ---------------------------------------------------------------------------
// MFMA flash attention v6: gemm64-style staging — async global_load_lds,
// double-buffered K/V tiles, ONE barrier per tile. K/V tiles stored as two
// 32-u16-wide halves ([key][32] / [d][32], 64B rows — m97-proven
// conflict-free layout, no padding so global_load_lds dest works).
//   S^T = K·Q^T ; O^T = V^T·P^T  (no-max exp; split-K partials sum linearly)
// Block = 4 waves = 4 q-heads of one kv-head; QB=32 queries; CH=512 chunk.
// Grid (SEQ/QB=64 reversed, NKV, NCH=4).
// ---------------------------------------------------------------------------
__global__ __launch_bounds__(256) void attn_kernel(const u16* __restrict__ Qb,
                                                   const u16* __restrict__ Kb,
                                                   const u16* __restrict__ VTg,
                                                   float* __restrict__ Opart,
                                                   float* __restrict__ lpart) {
    __shared__ u16 Ks[2][2][64 * 32];   // [buf][d-half][key*32]
    __shared__ u16 Vs[2][2][64 * 32];   // [buf][key-half][d*32]
    __shared__ u16 Pst[4][QB * PSTR];   // per-wave [q][key]

    const int tid  = threadIdx.x;
    const int lane = tid & 63;
    const int w    = tid >> 6;
    const int c    = lane & 15;
    const int quad = lane >> 4;
    const int kh   = blockIdx.y;
    const int z    = blockIdx.z;
    const int qt   = (SEQ / QB - 1) - (int)blockIdx.x;   // heavy first
    const int q0   = qt * QB;
    const int h    = kh * GQ + w;

    const int kstart = z * CH;
    const int klim   = q0 + QB;
    if (kstart >= klim) return;                 // empty chunk
    const int kend   = (klim < kstart + CH) ? klim : (kstart + CH);
    const int ntiles = (kend - kstart + KT - 1) / KT;

    bf16x8 qf[2][2];
    #pragma unroll
    for (int g = 0; g < 2; ++g)
        #pragma unroll
        for (int ks = 0; ks < 2; ++ks)
            qf[g][ks] = *(const bf16x8*)&Qb[(size_t)(q0 + g * 16 + c) * HID + h * DH + ks * 32 + quad * 8];

    f32x4 accO[4][2];
    #pragma unroll
    for (int nt = 0; nt < 4; ++nt)
        #pragma unroll
        for (int g = 0; g < 2; ++g)
            accO[nt][g] = (f32x4){0.f, 0.f, 0.f, 0.f};
    float l[2] = {0.f, 0.f};

    // staging: wave w covers half hf = w>>1, row-groups g0, g0+1 (16 rows each)
    const int hf = w >> 1;
    const int g0 = (w & 1) * 2;
    const int srow = (lane >> 2);        // 0..15 within group
    const int scol = (lane & 3) * 8;     // 0,8,16,24 u16

    // prologue: stage tile 0 into buf 0
    {
        #pragma unroll
        for (int gi = 0; gi < 2; ++gi) {
            const int g = g0 + gi;
            load_lds16(Kb + ((size_t)kh * SEQ + kstart + g * 16 + srow) * DH + hf * 32 + scol,
                       &Ks[0][hf][(g * 16) * 32]);
            load_lds16(VTg + ((size_t)kh * DH + g * 16 + srow) * SEQ + kstart + hf * 32 + scol,
                       &Vs[0][hf][(g * 16) * 32]);
        }
    }

    for (int t = 0; t < ntiles; ++t) {
        const int kt0 = kstart + t * KT;
        __syncthreads();   // drains tile t's async loads; buf[(t+1)&1] free
        if (t + 1 < ntiles) {
            const int nk = kt0 + KT;
            const int nb = (t + 1) & 1;
            #pragma unroll
            for (int gi = 0; gi < 2; ++gi) {
                const int g = g0 + gi;
                load_lds16(Kb + ((size_t)kh * SEQ + nk + g * 16 + srow) * DH + hf * 32 + scol,
                           &Ks[nb][hf][(g * 16) * 32]);
                load_lds16(VTg + ((size_t)kh * DH + g * 16 + srow) * SEQ + nk + hf * 32 + scol,
                           &Vs[nb][hf][(g * 16) * 32]);
            }
        }
        const int b = t & 1;

        // ---- S^T = K·Q^T: 4 key-frags x 2 d-halves x 2 q-frags
        f32x4 accS[4][2];
        #pragma unroll
        for (int nS = 0; nS < 4; ++nS)
            #pragma unroll
            for (int g = 0; g < 2; ++g)
                accS[nS][g] = (f32x4){0.f, 0.f, 0.f, 0.f};
        #pragma unroll
        for (int nS = 0; nS < 4; ++nS)
            #pragma unroll
            for (int ks = 0; ks < 2; ++ks) {
                const bf16x8 kf = *(const bf16x8*)&Ks[b][ks][(nS * 16 + c) * 32 + quad * 8];
                #pragma unroll
                for (int g = 0; g < 2; ++g)
                    accS[nS][g] = __builtin_amdgcn_mfma_f32_16x16x32_bf16(kf, qf[g][ks], accS[nS][g], 0, 0, 0);
            }

        // ---- mask + exp (row=key, col=q); per-column l; packed P^T
        #pragma unroll
        for (int g = 0; g < 2; ++g) {
            const int q = q0 + g * 16 + c;
            #pragma unroll
            for (int nS = 0; nS < 4; ++nS) {
                const int key = kt0 + nS * 16 + quad * 4;
                const float p0 = (key + 0 <= q) ? __expf(accS[nS][g][0]) : 0.f;
                const float p1 = (key + 1 <= q) ? __expf(accS[nS][g][1]) : 0.f;
                const float p2 = (key + 2 <= q) ? __expf(accS[nS][g][2]) : 0.f;
                const float p3 = (key + 3 <= q) ? __expf(accS[nS][g][3]) : 0.f;
                l[g] += (p0 + p1) + (p2 + p3);
                u32* dst = (u32*)&Pst[w][(g * 16 + c) * PSTR + nS * 16 + quad * 4];
                dst[0] = pk2bf(p0, p1);
                dst[1] = pk2bf(p2, p3);
            }
        }
        __threadfence_block();   // same-wave LDS write->read ordering

        // ---- O^T += V^T·P^T: 4 d-frags x 2 key-halves x 2 q-frags
        #pragma unroll
        for (int ks2 = 0; ks2 < 2; ++ks2) {
            bf16x8 pf[2];
            #pragma unroll
            for (int g = 0; g < 2; ++g)
                pf[g] = *(const bf16x8*)&Pst[w][(g * 16 + c) * PSTR + ks2 * 32 + quad * 8];
            #pragma unroll
            for (int nt = 0; nt < 4; ++nt) {
                const bf16x8 vf = *(const bf16x8*)&Vs[b][ks2][(nt * 16 + c) * 32 + quad * 8];
                #pragma unroll
                for (int g = 0; g < 2; ++g)
                    accO[nt][g] = __builtin_amdgcn_mfma_f32_16x16x32_bf16(vf, pf[g], accO[nt][g], 0, 0, 0);
            }
        }
    }

    #pragma unroll
    for (int g = 0; g < 2; ++g) {
        float lg = l[g];
        lg += __shfl_xor(lg, 16);
        lg += __shfl_xor(lg, 32);
        if (quad == 0)
            lpart[((size_t)z * SEQ + q0 + g * 16 + c) * NH + h] = lg;

        float* Op = Opart + ((size_t)z * SEQ + q0 + g * 16 + c) * HID + h * DH;
        #pragma unroll
        for (int nt = 0; nt < 4; ++nt)
            *(f32x4*)&Op[nt * 16 + quad * 4] = accO[nt][g];
    }
}

// ---------------------------------------------------------------------------
// Merge split-K partials: At[q] = sum_z O_z[q] / sum_z l_z[q], bf16.
// ---------------------------------------------------------------------------
__global__ __launch_bounds__(256) void attn_reduce(const float* __restrict__ Opart,
                                                   const float* __restrict__ lpart,
                                                   u16* __restrict__ At) {
    const int idx = blockIdx.x * 256 + threadIdx.x;   // float4 index
    const int q  = idx >> 8;
    const int h  = (idx & 255) >> 4;
    const int klim = (q & ~(QB - 1)) + QB;
    float4 o = ((const float4*)Opart)[idx];
    float  l = lpart[q * NH + h];
    #pragma unroll
    for (int z = 1; z < NCH; ++z) {
        if (z * CH < klim) {
            const float4 o1 = ((const float4*)Opart)[idx + z * (SEQ * HID / 4)];
            o.x += o1.x; o.y += o1.y; o.z += o1.z; o.w += o1.w;
            l += lpart[(z * SEQ + q) * NH + h];
        }
    }
    const float inv = 1.0f / l;
    ushort4 r;
    r.x = f2bf(o.x * inv); r.y = f2bf(o.y * inv);
    r.z = f2bf(o.z * inv); r.w = f2bf(o.w * inv);
    ((ushort4*)At)[idx] = r;
}

// ---------------------------------------------------------------------------
extern "C" void kernel_launch(void* const* d_in, const int* in_sizes, int n_in,
                              void* d_out, int out_size, void* d_ws, size_t ws_size,
                              hipStream_t stream) {
    const float* X  = (const float*)d_in[0];
    const float* Wq = (const float*)d_in[1];
    const float* Wk = (const float*)d_in[2];
    const float* Wv = (const float*)d_in[3];
    const float* Wo = (const float*)d_in[4];
    float* out = (float*)d_out;

    // workspace layout
    u16* Wt     = (u16*)d_ws;                        // 1536 x 1024 bf16
    u16* WoT    = Wt + (size_t)NQKV * HID;           // 1024 x 1024
    u16* Xb     = WoT + (size_t)HID * HID;           // 2048 x 1024
    u16* At     = Xb + (size_t)SEQ * HID;            // 2048 x 1024
    u16* Qb     = At + (size_t)SEQ * HID;            // 2048 x 1024
    u16* Kb     = Qb + (size_t)SEQ * HID;            // 4 x 2048 x 64
    u16* VTg    = Kb + (size_t)NKV * SEQ * DH;       // 4 x 64 x 2048
    float* Opart = (float*)(VTg + (size_t)NKV * DH * SEQ);  // NCH x 2048 x 1024 f32
    float* lpart = Opart + (size_t)NCH * SEQ * HID;  // NCH x 2048 x 16 f32

    dim3 blk(256);

    setup<<<dim3(64, 32, 5), blk, 0, stream>>>(X, Wq, Wk, Wv, Wo, Xb, Wt, WoT);

    gemm_qkv<<<dim3(NQKV / 64, SEQ / 64), blk, 0, stream>>>(Xb, Wt, Qb, Kb, VTg);

    attn_kernel<<<dim3(SEQ / QB, NKV, NCH), blk, 0, stream>>>(Qb, Kb, VTg, Opart, lpart);

    attn_reduce<<<(SEQ * HID / 4) / 256, blk, 0, stream>>>(Opart, lpart, At);

    gemm64<<<dim3(HID / 64, SEQ / 64), blk, 0, stream>>>(At, WoT, out, HID, HID);
}